// Round 5
// baseline (60.306 us; speedup 1.0000x reference)
//
#include <hip/hip_runtime.h>
#include <hip/hip_cooperative_groups.h>
#include <math.h>

namespace cg = cooperative_groups;

#define GROUP 16
#define BLOCK 256   // GROUP*GROUP: one thread per (a,b) pair
#define SSTR  260   // LDS row stride in floats (1040B: 16B-aligned, breaks bank pow2)

// Single cooperative launch. One block per 16-row identity group:
//   phase 1: stage group tile in LDS, thread (a,b) computes dist^2(a,b),
//            16-lane shfl max -> per-row hardest intra/inter, block partial
//            hinge-sum -> partial[blockIdx.x]  (plain store, all slots written)
//   grid.sync()
//   phase 2: block 0 reduces the ngroups partials in fixed order -> mean.
// No atomics, no workspace init, deterministic.
__global__ __launch_bounds__(BLOCK) void vcl_coop_kernel(
    const float* __restrict__ q, const int* __restrict__ labels,
    const int* __restrict__ cams, float* __restrict__ partial,
    float* __restrict__ out, int N, int D, int ngroups) {

    const int tid = threadIdx.x;
    const int g0  = blockIdx.x * GROUP;
    const int a   = tid >> 4;
    const int b   = tid & 15;

    __shared__ float lds[GROUP * SSTR];
    const int D4 = D >> 2;

    // cooperative coalesced tile load: GROUP*D floats
    const int nf4 = GROUP * D4;
    for (int idx = tid; idx < nf4; idx += BLOCK) {
        int row = idx / D4;
        int col = idx - row * D4;
        int gr  = g0 + row;
        float4 v = (gr < N) ? *(const float4*)(q + (size_t)gr * D + col * 4)
                            : make_float4(0.f, 0.f, 0.f, 0.f);
        *(float4*)(lds + row * SSTR + col * 4) = v;
    }
    __syncthreads();

    const int ga = g0 + a, gb = g0 + b;
    const bool oka = ga < N, okb = gb < N;
    const int la = oka ? labels[ga] : -1;
    const int lb = okb ? labels[gb] : -2;
    const int ca = oka ? cams[ga] : -1;
    const int cb = okb ? cams[gb] : -2;
    const bool pos = oka && okb && (la == lb);

    const float4* A = (const float4*)(lds + a * SSTR);
    const float4* B = (const float4*)(lds + b * SSTR);
    float s = 0.f;
    #pragma unroll 8
    for (int d = 0; d < D4; ++d) {
        float4 x = A[d], y = B[d];
        float dx = x.x - y.x, dy = x.y - y.y, dz = x.z - y.z, dw = x.w - y.w;
        s += dx * dx; s += dy * dy; s += dz * dz; s += dw * dw;
    }

    float intra2 = (pos && ca == cb) ? s : -1.f;   // max of dist^2; -1 = empty
    float inter2 = (pos && ca != cb) ? s : -1.f;
    #pragma unroll
    for (int off = 1; off < 16; off <<= 1) {
        intra2 = fmaxf(intra2, __shfl_xor(intra2, off));
        inter2 = fmaxf(inter2, __shfl_xor(inter2, off));
    }

    __shared__ float hs[GROUP];
    if (b == 0) {
        float hinge = 0.f;
        if (oka) {
            float hard_intra = (intra2 < 0.f) ? 1.0f : sqrtf(fmaxf(intra2, 1e-12f));
            float hard_inter = (inter2 < 0.f) ? hard_intra : sqrtf(fmaxf(inter2, 1e-12f));
            hinge = fmaxf(0.f, hard_inter - hard_intra + 0.1f);
        }
        hs[a] = hinge;
    }
    __syncthreads();

    if (tid == 0) {
        float part = 0.f;
        #pragma unroll
        for (int r = 0; r < GROUP; ++r) part += hs[r];
        partial[blockIdx.x] = part;
    }

    cg::this_grid().sync();

    if (blockIdx.x == 0) {
        float s2 = 0.f;
        for (int j = tid; j < ngroups; j += BLOCK) s2 += partial[j];
        #pragma unroll
        for (int off = 32; off; off >>= 1) s2 += __shfl_xor(s2, off);
        __shared__ float sw[4];
        if ((tid & 63) == 0) sw[tid >> 6] = s2;
        __syncthreads();
        if (tid == 0) out[0] = (sw[0] + sw[1] + sw[2] + sw[3]) / (float)N;
    }
}

extern "C" void kernel_launch(void* const* d_in, const int* in_sizes, int n_in,
                              void* d_out, int out_size, void* d_ws, size_t ws_size,
                              hipStream_t stream) {
    const float* q      = (const float*)d_in[0];
    const int*   labels = (const int*)d_in[1];
    const int*   cams   = (const int*)d_in[2];
    float*       out    = (float*)d_out;

    int N = in_sizes[1];
    int D = in_sizes[0] / N;
    int ngroups = (N + GROUP - 1) / GROUP;

    float* partial = (float*)d_ws;   // ngroups floats, fully rewritten each call

    void* args[] = {(void*)&q, (void*)&labels, (void*)&cams, (void*)&partial,
                    (void*)&out, (void*)&N, (void*)&D, (void*)&ngroups};
    hipLaunchCooperativeKernel((const void*)vcl_coop_kernel,
                               dim3(ngroups), dim3(BLOCK), args, 0, stream);
}

// Round 6
// 12.829 us; speedup vs baseline: 4.7007x; 4.7007x over previous
//
#include <hip/hip_runtime.h>
#include <math.h>

#define GROUP 16
#define BLOCK 256   // GROUP*GROUP: one thread per (a,b) pair
#define SSTR  260   // LDS row stride in floats (1040B: 16B-aligned, breaks pow2 banks)

// One block per 16-row identity group (labels sorted & tile-aligned; label
// equality re-checked per pair). Thread (a,b) computes dist^2(a,b) from the
// LDS-staged tile; 16-lane shfl max -> per-row hardest intra/inter positive;
// block hinge-sum -> partial[blockIdx.x] (plain store, every slot written
// every call -> no init, no atomics, deterministic).
__global__ __launch_bounds__(BLOCK) void vcl_group_kernel(
    const float* __restrict__ q, const int* __restrict__ labels,
    const int* __restrict__ cams, float* __restrict__ partial,
    int N, int D) {

    const int tid = threadIdx.x;
    const int g0  = blockIdx.x * GROUP;
    const int a   = tid >> 4;
    const int b   = tid & 15;

    __shared__ float lds[GROUP * SSTR];
    const int D4 = D >> 2;

    // cooperative coalesced tile load: GROUP*D floats
    const int nf4 = GROUP * D4;
    for (int idx = tid; idx < nf4; idx += BLOCK) {
        int row = idx / D4;
        int col = idx - row * D4;
        int gr  = g0 + row;
        float4 v = (gr < N) ? *(const float4*)(q + (size_t)gr * D + col * 4)
                            : make_float4(0.f, 0.f, 0.f, 0.f);
        *(float4*)(lds + row * SSTR + col * 4) = v;
    }
    __syncthreads();

    const int ga = g0 + a, gb = g0 + b;
    const bool oka = ga < N, okb = gb < N;
    const int la = oka ? labels[ga] : -1;
    const int lb = okb ? labels[gb] : -2;
    const int ca = oka ? cams[ga] : -1;
    const int cb = okb ? cams[gb] : -2;
    const bool pos = oka && okb && (la == lb);

    const float4* A = (const float4*)(lds + a * SSTR);
    const float4* B = (const float4*)(lds + b * SSTR);
    float s = 0.f;
    #pragma unroll 8
    for (int d = 0; d < D4; ++d) {
        float4 x = A[d], y = B[d];
        float dx = x.x - y.x, dy = x.y - y.y, dz = x.z - y.z, dw = x.w - y.w;
        s += dx * dx; s += dy * dy; s += dz * dz; s += dw * dw;
    }

    float intra2 = (pos && ca == cb) ? s : -1.f;   // max of dist^2; -1 = empty
    float inter2 = (pos && ca != cb) ? s : -1.f;
    #pragma unroll
    for (int off = 1; off < 16; off <<= 1) {
        intra2 = fmaxf(intra2, __shfl_xor(intra2, off));
        inter2 = fmaxf(inter2, __shfl_xor(inter2, off));
    }

    __shared__ float hs[GROUP];
    if (b == 0) {
        float hinge = 0.f;
        if (oka) {
            float hard_intra = (intra2 < 0.f) ? 1.0f : sqrtf(fmaxf(intra2, 1e-12f));
            float hard_inter = (inter2 < 0.f) ? hard_intra : sqrtf(fmaxf(inter2, 1e-12f));
            hinge = fmaxf(0.f, hard_inter - hard_intra + 0.1f);
        }
        hs[a] = hinge;
    }
    __syncthreads();

    if (tid == 0) {
        float part = 0.f;
        #pragma unroll
        for (int r = 0; r < GROUP; ++r) part += hs[r];
        partial[blockIdx.x] = part;
    }
}

__global__ __launch_bounds__(512) void vcl_reduce_kernel(const float* __restrict__ partial,
                                                         float* __restrict__ out,
                                                         int ngroups, int N) {
    const int tid = threadIdx.x;
    float s = 0.f;
    for (int j = tid; j < ngroups; j += 512) s += partial[j];
    #pragma unroll
    for (int off = 32; off; off >>= 1) s += __shfl_xor(s, off);
    __shared__ float sw[8];
    if ((tid & 63) == 0) sw[tid >> 6] = s;
    __syncthreads();
    if (tid == 0) {
        float r = 0.f;
        #pragma unroll
        for (int w = 0; w < 8; ++w) r += sw[w];
        out[0] = r / (float)N;
    }
}

extern "C" void kernel_launch(void* const* d_in, const int* in_sizes, int n_in,
                              void* d_out, int out_size, void* d_ws, size_t ws_size,
                              hipStream_t stream) {
    const float* q      = (const float*)d_in[0];
    const int*   labels = (const int*)d_in[1];
    const int*   cams   = (const int*)d_in[2];
    float*       out    = (float*)d_out;

    const int N = in_sizes[1];
    const int D = in_sizes[0] / N;
    const int ngroups = (N + GROUP - 1) / GROUP;

    float* partial = (float*)d_ws;   // ngroups floats, fully rewritten each call

    vcl_group_kernel<<<ngroups, BLOCK, 0, stream>>>(q, labels, cams, partial, N, D);
    vcl_reduce_kernel<<<1, 512, 0, stream>>>(partial, out, ngroups, N);
}